// Round 4
// baseline (4660.653 us; speedup 1.0000x reference)
//
#include <hip/hip_runtime.h>
#include <hip/hip_bf16.h>
#include <math.h>

// Problem constants
#define B_   2048
#define T_   48
#define H_   512
#define E_   256
#define V_   128
#define ENC_ 1024
#define H3_  1536   // 3*H
#define BH_  (B_ * H_)
#define NBLK 256    // persistent grid size (must be <= co-resident capacity)

typedef __attribute__((ext_vector_type(8))) short bf16x8;   // 8 bf16 = 4 VGPRs
typedef __attribute__((ext_vector_type(4))) float f32x4;
typedef unsigned short ushort_t;

#if defined(__has_builtin)
#if __has_builtin(__builtin_amdgcn_global_load_lds)
#define HAVE_ASYNC 1
#endif
#endif
#ifndef HAVE_ASYNC
#define HAVE_ASYNC 0
#endif

__device__ __forceinline__ void stage_chunk(const ushort_t* __restrict__ g,
                                            ushort_t* l, int lane)
{
#if HAVE_ASYNC
    __builtin_amdgcn_global_load_lds(
        (const __attribute__((address_space(1))) unsigned int*)g,
        (__attribute__((address_space(3))) unsigned int*)l, 16, 0, 0);
#else
    *(bf16x8*)(l + lane * 8) = *(const bf16x8*)g;
#endif
}

__device__ __forceinline__ float sigmoidf_(float x) { return 1.0f / (1.0f + expf(-x)); }

// ---------------------------------------------------------------------------
// Device-scope grid barrier (all NBLK blocks co-resident). Sense via gen ctr.
// ---------------------------------------------------------------------------
__device__ __forceinline__ void grid_barrier(unsigned* cnt, unsigned* gen)
{
    __syncthreads();
    if (threadIdx.x == 0) {
        __threadfence();
        unsigned my = __hip_atomic_load(gen, __ATOMIC_RELAXED, __HIP_MEMORY_SCOPE_AGENT);
        unsigned old = __hip_atomic_fetch_add(cnt, 1u, __ATOMIC_ACQ_REL, __HIP_MEMORY_SCOPE_AGENT);
        if (old == (unsigned)NBLK - 1) {
            __hip_atomic_store(cnt, 0u, __ATOMIC_RELAXED, __HIP_MEMORY_SCOPE_AGENT);
            __hip_atomic_fetch_add(gen, 1u, __ATOMIC_ACQ_REL, __HIP_MEMORY_SCOPE_AGENT);
        } else {
            while (__hip_atomic_load(gen, __ATOMIC_ACQUIRE, __HIP_MEMORY_SCOPE_AGENT) == my)
                __builtin_amdgcn_s_sleep(1);
        }
        __threadfence();
    }
    __syncthreads();
}

// ---------------------------------------------------------------------------
// fp32 tiled GEMM (setup only): C[M,N] = A[M,K] @ B[K,N] (+ bias[N])
// 32x64 tile -> 2x more blocks than 64x64 (latency-bound setup GEMMs).
// ---------------------------------------------------------------------------
__global__ __launch_bounds__(256) void gemm_f32(
    const float* __restrict__ A, const float* __restrict__ Bm,
    const float* __restrict__ bias, float* __restrict__ C,
    int M, int N, int K)
{
    __shared__ float As[16][34];
    __shared__ float Bs[16][68];

    const int tid = threadIdx.x;
    const int bm = blockIdx.y * 32;
    const int bn = blockIdx.x * 64;
    const int tm = (tid >> 4) * 2;     // 0..30
    const int tn = (tid & 15) * 4;     // 0..60
    const int lmA = tid >> 3;          // 0..31
    const int lkA = (tid & 7) * 2;     // 0..14
    const int lkB = tid >> 4;          // 0..15
    const int lnB = (tid & 15) * 4;

    float acc[2][4] = {};

    for (int k0 = 0; k0 < K; k0 += 16) {
        float2 av  = *(const float2*)(A  + (size_t)(bm + lmA) * K + (k0 + lkA));
        float4 bv4 = *(const float4*)(Bm + (size_t)(k0 + lkB) * N + (bn + lnB));
        As[lkA + 0][lmA] = av.x;
        As[lkA + 1][lmA] = av.y;
        *(float4*)&Bs[lkB][lnB] = bv4;
        __syncthreads();

        #pragma unroll
        for (int k = 0; k < 16; ++k) {
            float2 a = *(const float2*)&As[k][tm];
            float4 b = *(const float4*)&Bs[k][tn];
            acc[0][0] += a.x * b.x; acc[0][1] += a.x * b.y; acc[0][2] += a.x * b.z; acc[0][3] += a.x * b.w;
            acc[1][0] += a.y * b.x; acc[1][1] += a.y * b.y; acc[1][2] += a.y * b.z; acc[1][3] += a.y * b.w;
        }
        __syncthreads();
    }

    #pragma unroll
    for (int r = 0; r < 2; ++r)
        #pragma unroll
        for (int c = 0; c < 4; ++c) {
            float v = acc[r][c];
            if (bias) v += bias[bn + tn + c];
            C[(size_t)(bm + tm + r) * N + (bn + tn + c)] = v;
        }
}

// ---------------------------------------------------------------------------
// Weight transpose + bf16 convert: W[K][N] fp32 -> Wt[N][K] bf16 (one-time)
// ---------------------------------------------------------------------------
__global__ __launch_bounds__(256) void transpose_to_bf16(
    const float* __restrict__ W, __hip_bfloat16* __restrict__ Wt, int K, int N)
{
    __shared__ float tile[32][33];
    const int bk = blockIdx.y * 32, bn = blockIdx.x * 32;
    const int tx = threadIdx.x & 31, ty = threadIdx.x >> 5;
    #pragma unroll
    for (int i = ty; i < 32; i += 8)
        tile[i][tx] = W[(size_t)(bk + i) * N + (bn + tx)];
    __syncthreads();
    #pragma unroll
    for (int i = ty; i < 32; i += 8)
        Wt[(size_t)(bn + i) * K + (bk + tx)] = __float2bfloat16(tile[tx][i]);
}

__global__ __launch_bounds__(256) void init_bf16_mirrors(
    const float* __restrict__ hf, ushort_t* __restrict__ h1b, ushort_t* __restrict__ h2b)
{
    int idx = blockIdx.x * 256 + threadIdx.x;   // over BH
    __hip_bfloat16 a = __float2bfloat16(hf[idx]);
    __hip_bfloat16 b = __float2bfloat16(hf[BH_ + idx]);
    h1b[idx] = *(ushort_t*)&a;
    h2b[idx] = *(ushort_t*)&b;
}

// ---------------------------------------------------------------------------
// Persistent GRU kernel: all T steps, grid = 256 blocks x 512 threads.
// Per block: 128 batch rows (mi) x 32 hidden units (ii), all 3 gates.
// Per step: [L1 gemm+gates] gbar [L2 dual-gemm+gates] gbar [vocab softmax].
// LDS (57344 B): L1 dbuf 2x7168 ush @0; L2 dbuf 2x14336 ush @0;
//                P3 hP 8192 ush @14336, lgA 2048 @22528, lgB 2048 @24576.
// ---------------------------------------------------------------------------
__global__ __launch_bounds__(512, 2) void gru_persistent(
    const int* __restrict__ tgt,
    const float* __restrict__ xe1,            // [V,3H] embed@k1 + b1[0]
    const ushort_t* __restrict__ rk1t,        // [3H,H] bf16
    const ushort_t* __restrict__ k2t,         // [3H,H] bf16
    const ushort_t* __restrict__ rk2t,        // [3H,H] bf16
    const float* __restrict__ rb1,            // b1[1]
    const float* __restrict__ bx2,            // b2[0]
    const float* __restrict__ br2,            // b2[1]
    const float* __restrict__ Wv,             // [H,V] fp32
    const float* __restrict__ bv,             // [V]
    float* __restrict__ hf,                   // [2 buf][2 layer][BH] fp32
    ushort_t* __restrict__ h1b,               // [2][BH] bf16
    ushort_t* __restrict__ h2b,               // [2][BH] bf16
    float* __restrict__ out,                  // [B,T,V]
    unsigned* __restrict__ bar)               // {cnt, gen}
{
    __shared__ __attribute__((aligned(16))) ushort_t lds[28672];

    const int tid  = threadIdx.x;
    const int lane = tid & 63;
    const int w    = tid >> 6;        // 0..7
    const int ln   = lane & 15;
    const int kg   = lane >> 4;       // 0..3
    const int wr   = w >> 1;          // 0..3 (row quarter)
    const int wc   = w & 1;           // 0..1 (i half)
    const int bid  = blockIdx.x;
    const int m0   = (bid >> 4) * 128;
    const int i0   = (bid & 15) * 32;
    const int i    = i0 + wc * 16 + ln;
    const int crow = lane >> 2;          // 0..15 within 16-row chunk
    const int ckof = (lane & 3) * 8;     // k element offset within 32

    unsigned* cnt = bar;
    unsigned* gen = bar + 1;

    for (int t = 0; t < T_; ++t) {
        const int cur = t & 1, nxt = cur ^ 1;
        const float*    h1f_c = hf + (size_t)cur * 2 * BH_;
        float*          h1f_n = hf + (size_t)nxt * 2 * BH_;
        const float*    h2f_c = h1f_c + BH_;
        float*          h2f_n = h1f_n + BH_;
        const ushort_t* h1b_c = h1b + (size_t)cur * BH_;
        ushort_t*       h1b_n = h1b + (size_t)nxt * BH_;
        const ushort_t* h2b_c = h2b + (size_t)cur * BH_;
        ushort_t*       h2b_n = h2b + (size_t)nxt * BH_;

        // ================= phase 1: layer-1 GEMM + gates =================
        {
            // prefetch epilogue operands (fly during the K-loop)
            int ids[8]; float hvs[8], xz[8], xr[8], xh[8];
            #pragma unroll
            for (int fm = 0; fm < 2; ++fm)
                #pragma unroll
                for (int r = 0; r < 4; ++r) {
                    const int j = fm * 4 + r;
                    const int b = m0 + wr * 32 + fm * 16 + kg * 4 + r;
                    ids[j] = tgt[(size_t)b * T_ + t];
                    hvs[j] = h1f_c[(size_t)b * H_ + i];
                    const float* xg = xe1 + (size_t)ids[j] * H3_;
                    xz[j] = xg[i]; xr[j] = xg[H_ + i]; xh[j] = xg[2 * H_ + i];
                }

            auto stage1 = [&](int sel, int k0) {
                ushort_t* base = lds + sel * 7168;
                for (int c = w; c < 14; c += 8) {
                    const ushort_t* g;
                    ushort_t* l;
                    if (c < 8) {
                        g = h1b_c + (size_t)(m0 + c * 16 + crow) * H_ + k0 + ckof;
                        l = base + c * 512;
                    } else {
                        const int d = c - 8;   // gate = d>>1, half = d&1
                        g = rk1t + (size_t)((d >> 1) * H_ + i0 + (d & 1) * 16 + crow) * H_ + k0 + ckof;
                        l = base + 4096 + d * 512;
                    }
                    stage_chunk(g, l, lane);
                }
            };

            f32x4 acc[2][3] = {};
            stage1(0, 0);
            for (int kt = 0; kt < 16; ++kt) {
                __syncthreads();
                if (kt < 15) stage1((kt + 1) & 1, (kt + 1) * 32);
                const ushort_t* base = lds + (kt & 1) * 7168;
                bf16x8 af[2], bb[3];
                #pragma unroll
                for (int fm = 0; fm < 2; ++fm)
                    af[fm] = *(const bf16x8*)(base + (wr * 32 + fm * 16 + ln) * 32 + kg * 8);
                #pragma unroll
                for (int g = 0; g < 3; ++g)
                    bb[g] = *(const bf16x8*)(base + 4096 + g * 1024 + (wc * 16 + ln) * 32 + kg * 8);
                #pragma unroll
                for (int fm = 0; fm < 2; ++fm)
                    #pragma unroll
                    for (int g = 0; g < 3; ++g)
                        acc[fm][g] = __builtin_amdgcn_mfma_f32_16x16x32_bf16(
                            af[fm], bb[g], acc[fm][g], 0, 0, 0);
            }

            const float rbz = rb1[i], rbr = rb1[H_ + i], rbh = rb1[2 * H_ + i];
            #pragma unroll
            for (int fm = 0; fm < 2; ++fm)
                #pragma unroll
                for (int r = 0; r < 4; ++r) {
                    const int j = fm * 4 + r;
                    const int b = m0 + wr * 32 + fm * 16 + kg * 4 + r;
                    float z  = sigmoidf_(xz[j] + acc[fm][0][r] + rbz);
                    float rr = sigmoidf_(xr[j] + acc[fm][1][r] + rbr);
                    float hh = tanhf(xh[j] + rr * (acc[fm][2][r] + rbh));
                    float hn = (ids[j] != 0) ? (z * hvs[j] + (1.0f - z) * hh) : hvs[j];
                    h1f_n[(size_t)b * H_ + i] = hn;
                    ((__hip_bfloat16*)h1b_n)[(size_t)b * H_ + i] = __float2bfloat16(hn);
                }
        }
        grid_barrier(cnt, gen);

        // ================= phase 2: layer-2 dual GEMM + gates =================
        {
            int ids[8]; float hvs[8];
            #pragma unroll
            for (int fm = 0; fm < 2; ++fm)
                #pragma unroll
                for (int r = 0; r < 4; ++r) {
                    const int j = fm * 4 + r;
                    const int b = m0 + wr * 32 + fm * 16 + kg * 4 + r;
                    ids[j] = tgt[(size_t)b * T_ + t];
                    hvs[j] = h2f_c[(size_t)b * H_ + i];
                }

            auto stage2 = [&](int sel, int k0) {
                ushort_t* base = lds + sel * 14336;
                for (int c = w; c < 28; c += 8) {
                    const ushort_t* g;
                    ushort_t* l;
                    if (c < 8) {                     // A0 = s1 (h1b_nxt)
                        g = h1b_n + (size_t)(m0 + c * 16 + crow) * H_ + k0 + ckof;
                        l = base + c * 512;
                    } else if (c < 16) {             // A1 = h2 state
                        const int d = c - 8;
                        g = h2b_c + (size_t)(m0 + d * 16 + crow) * H_ + k0 + ckof;
                        l = base + 4096 + d * 512;
                    } else if (c < 22) {             // B0 = k2t strips
                        const int d = c - 16;
                        g = k2t + (size_t)((d >> 1) * H_ + i0 + (d & 1) * 16 + crow) * H_ + k0 + ckof;
                        l = base + 8192 + d * 512;
                    } else {                         // B1 = rk2t strips
                        const int d = c - 22;
                        g = rk2t + (size_t)((d >> 1) * H_ + i0 + (d & 1) * 16 + crow) * H_ + k0 + ckof;
                        l = base + 11264 + d * 512;
                    }
                    stage_chunk(g, l, lane);
                }
            };

            f32x4 acc0[2][3] = {};
            f32x4 acc1[2][3] = {};
            stage2(0, 0);
            for (int kt = 0; kt < 16; ++kt) {
                __syncthreads();
                if (kt < 15) stage2((kt + 1) & 1, (kt + 1) * 32);
                const ushort_t* base = lds + (kt & 1) * 14336;
                bf16x8 a0[2], a1[2], b0[3], b1[3];
                #pragma unroll
                for (int fm = 0; fm < 2; ++fm) {
                    a0[fm] = *(const bf16x8*)(base + (wr * 32 + fm * 16 + ln) * 32 + kg * 8);
                    a1[fm] = *(const bf16x8*)(base + 4096 + (wr * 32 + fm * 16 + ln) * 32 + kg * 8);
                }
                #pragma unroll
                for (int g = 0; g < 3; ++g) {
                    b0[g] = *(const bf16x8*)(base + 8192  + g * 1024 + (wc * 16 + ln) * 32 + kg * 8);
                    b1[g] = *(const bf16x8*)(base + 11264 + g * 1024 + (wc * 16 + ln) * 32 + kg * 8);
                }
                #pragma unroll
                for (int fm = 0; fm < 2; ++fm)
                    #pragma unroll
                    for (int g = 0; g < 3; ++g) {
                        acc0[fm][g] = __builtin_amdgcn_mfma_f32_16x16x32_bf16(
                            a0[fm], b0[g], acc0[fm][g], 0, 0, 0);
                        acc1[fm][g] = __builtin_amdgcn_mfma_f32_16x16x32_bf16(
                            a1[fm], b1[g], acc1[fm][g], 0, 0, 0);
                    }
            }

            const float bxz = bx2[i], bxr = bx2[H_ + i], bxh = bx2[2 * H_ + i];
            const float brz = br2[i], brr = br2[H_ + i], brh = br2[2 * H_ + i];
            #pragma unroll
            for (int fm = 0; fm < 2; ++fm)
                #pragma unroll
                for (int r = 0; r < 4; ++r) {
                    const int j = fm * 4 + r;
                    const int b = m0 + wr * 32 + fm * 16 + kg * 4 + r;
                    float z  = sigmoidf_((acc0[fm][0][r] + bxz) + (acc1[fm][0][r] + brz));
                    float rr = sigmoidf_((acc0[fm][1][r] + bxr) + (acc1[fm][1][r] + brr));
                    float hh = tanhf((acc0[fm][2][r] + bxh) + rr * (acc1[fm][2][r] + brh));
                    float hn = (ids[j] != 0) ? (z * hvs[j] + (1.0f - z) * hh) : hvs[j];
                    h2f_n[(size_t)b * H_ + i] = hn;
                    ((__hip_bfloat16*)h2b_n)[(size_t)b * H_ + i] = __float2bfloat16(hn);
                }
        }
        grid_barrier(cnt, gen);

        // ================= phase 3: vocab projection + softmax =================
        {
            float* hP  = (float*)(lds + 14336);   // [8][512]
            float* lgA = (float*)(lds + 22528);   // [8][128] (k-half 0)
            float* lgB = (float*)(lds + 24576);   // [8][128] (k-half 1)
            const int rb0 = bid * 8;

            #pragma unroll
            for (int j = tid; j < 1024; j += 512)
                ((float4*)hP)[j] = ((const float4*)(h2f_n + (size_t)rb0 * H_))[j];
            __syncthreads();

            const int vg  = tid & 31;             // v = vg*4
            const int row = (tid >> 5) & 7;
            const int kh  = tid >> 8;             // 0,1
            const float* hrow  = hP + row * H_ + kh * 256;
            const float* wbase = Wv + (size_t)(kh * 256) * V_ + vg * 4;
            f32x4 a = {0.f, 0.f, 0.f, 0.f};
            #pragma unroll 8
            for (int k = 0; k < 256; ++k) {
                const float4 wv = *(const float4*)(wbase + (size_t)k * V_);
                const float hk = hrow[k];
                a[0] += hk * wv.x; a[1] += hk * wv.y; a[2] += hk * wv.z; a[3] += hk * wv.w;
            }
            float* lg = kh ? lgB : lgA;
            *(f32x4*)(lg + row * V_ + vg * 4) = a;
            __syncthreads();

            if (tid < 128) {
                const int srow = tid >> 4, seg = tid & 15;
                const float4 xa0 = ((const float4*)(lgA + srow * V_))[seg * 2];
                const float4 xa1 = ((const float4*)(lgA + srow * V_))[seg * 2 + 1];
                const float4 xb0 = ((const float4*)(lgB + srow * V_))[seg * 2];
                const float4 xb1 = ((const float4*)(lgB + srow * V_))[seg * 2 + 1];
                const float4 bb0 = ((const float4*)bv)[seg * 2];
                const float4 bb1 = ((const float4*)bv)[seg * 2 + 1];
                float l0 = xa0.x + xb0.x + bb0.x, l1 = xa0.y + xb0.y + bb0.y;
                float l2 = xa0.z + xb0.z + bb0.z, l3 = xa0.w + xb0.w + bb0.w;
                float l4 = xa1.x + xb1.x + bb1.x, l5 = xa1.y + xb1.y + bb1.y;
                float l6 = xa1.z + xb1.z + bb1.z, l7 = xa1.w + xb1.w + bb1.w;
                float m = fmaxf(fmaxf(fmaxf(l0, l1), fmaxf(l2, l3)),
                                fmaxf(fmaxf(l4, l5), fmaxf(l6, l7)));
                #pragma unroll
                for (int d = 1; d < 16; d <<= 1) m = fmaxf(m, __shfl_xor(m, d));
                float e0 = __expf(l0 - m), e1 = __expf(l1 - m), e2 = __expf(l2 - m), e3 = __expf(l3 - m);
                float e4 = __expf(l4 - m), e5 = __expf(l5 - m), e6 = __expf(l6 - m), e7 = __expf(l7 - m);
                float s = e0 + e1 + e2 + e3 + e4 + e5 + e6 + e7;
                #pragma unroll
                for (int d = 1; d < 16; d <<= 1) s += __shfl_xor(s, d);
                const float inv = 1.0f / s;
                float* op = out + ((size_t)(rb0 + srow) * T_ + t) * V_ + seg * 8;
                float4 o0 = {e0 * inv, e1 * inv, e2 * inv, e3 * inv};
                float4 o1 = {e4 * inv, e5 * inv, e6 * inv, e7 * inv};
                ((float4*)op)[0] = o0;
                ((float4*)op)[1] = o1;
            }
            // no barrier needed: next L1 uses LDS [0..14336), P3 used [14336..26624)
        }
    }
}

// ---------------------------------------------------------------------------
// Launch
// ---------------------------------------------------------------------------
extern "C" void kernel_launch(void* const* d_in, const int* in_sizes, int n_in,
                              void* d_out, int out_size, void* d_ws, size_t ws_size,
                              hipStream_t stream)
{
    const int*   tgt  = (const int*)  d_in[0];
    const float* enc  = (const float*)d_in[1];
    const float* Wi1  = (const float*)d_in[2];
    const float* Wi2  = (const float*)d_in[3];
    const float* emb  = (const float*)d_in[4];
    const float* k1   = (const float*)d_in[5];
    const float* rk1  = (const float*)d_in[6];
    const float* b1   = (const float*)d_in[7];
    const float* k2   = (const float*)d_in[8];
    const float* rk2  = (const float*)d_in[9];
    const float* b2   = (const float*)d_in[10];
    const float* Wv   = (const float*)d_in[11];
    const float* bv   = (const float*)d_in[12];
    float* out = (float*)d_out;

    // workspace (~29.5 MB)
    float* ws  = (float*)d_ws;
    float* xe1 = ws;                                   // [V,3H]
    float* hf  = xe1 + (size_t)V_ * H3_;               // [2][2][BH] fp32
    ushort_t* h1b  = (ushort_t*)(hf + (size_t)4 * BH_);// [2][BH]
    ushort_t* h2b  = h1b + (size_t)2 * BH_;            // [2][BH]
    ushort_t* rk1t = h2b + (size_t)2 * BH_;            // [3H,H]
    ushort_t* k2t  = rk1t + (size_t)H3_ * H_;
    ushort_t* rk2t = k2t  + (size_t)H3_ * H_;
    unsigned* bar  = (unsigned*)(rk2t + (size_t)H3_ * H_);   // {cnt, gen}

    dim3 blk(256);

    hipMemsetAsync(bar, 0, 2 * sizeof(unsigned), stream);

    // one-time weight transposes to bf16
    transpose_to_bf16<<<dim3(H3_ / 32, H_ / 32), blk, 0, stream>>>(rk1, (__hip_bfloat16*)rk1t, H_, H3_);
    transpose_to_bf16<<<dim3(H3_ / 32, H_ / 32), blk, 0, stream>>>(k2,  (__hip_bfloat16*)k2t,  H_, H3_);
    transpose_to_bf16<<<dim3(H3_ / 32, H_ / 32), blk, 0, stream>>>(rk2, (__hip_bfloat16*)rk2t, H_, H3_);

    // xe1 = embed_table @ k1 + b1[0]   (reassociated x1; gathered per (b,t))
    gemm_f32<<<dim3(H3_ / 64, V_ / 32), blk, 0, stream>>>(emb, k1, b1, xe1, V_, H3_, E_);
    // initial states: h01 -> hf[0][0], h02 -> hf[0][1]
    gemm_f32<<<dim3(H_ / 64, B_ / 32), blk, 0, stream>>>(enc, Wi1, nullptr, hf,       B_, H_, ENC_);
    gemm_f32<<<dim3(H_ / 64, B_ / 32), blk, 0, stream>>>(enc, Wi2, nullptr, hf + BH_, B_, H_, ENC_);
    init_bf16_mirrors<<<BH_ / 256, blk, 0, stream>>>(hf, h1b, h2b);

    // the whole recurrence + output in one persistent kernel
    gru_persistent<<<dim3(NBLK), dim3(512), 0, stream>>>(
        tgt, xe1, rk1t, k2t, rk2t,
        b1 + H3_, b2, b2 + H3_, Wv, bv,
        hf, h1b, h2b, out, bar);
}